// Round 7
// baseline (202.735 us; speedup 1.0000x reference)
//
#include <hip/hip_runtime.h>
#include <cstdint>

using u16 = unsigned short;
typedef __bf16 bf16x8 __attribute__((ext_vector_type(8)));
typedef __bf16 bf16x4 __attribute__((ext_vector_type(4)));
typedef float f32x4 __attribute__((ext_vector_type(4)));

#define MFMA16(a, b, c) __builtin_amdgcn_mfma_f32_16x16x32_bf16((a), (b), (c), 0, 0, 0)

__device__ __forceinline__ u16 f2bf(float f) {
  union { float f; uint32_t u; } c; c.f = f;
  uint32_t u = c.u;
  u += 0x7fffu + ((u >> 16) & 1u);   // RNE
  return (u16)(u >> 16);
}

#if __has_builtin(__builtin_amdgcn_global_load_lds)
#define GLOAD_LDS16(g, l)                                                      \
  __builtin_amdgcn_global_load_lds(                                            \
      (__attribute__((address_space(1))) void*)(g),                            \
      (__attribute__((address_space(3))) void*)(l), 16, 0, 0)
#else
#define GLOAD_LDS16(g, l) do { *(uint4*)(l) = *(const uint4*)(g); } while (0)
#endif

// ---------------- fused prep: x->bf16, w_qkv^T->bf16, w_out^T->bf16 --------
__global__ __launch_bounds__(256) void prep(
    const float* __restrict__ x, const float* __restrict__ w_qkv,
    const float* __restrict__ w_out, u16* __restrict__ xb,
    u16* __restrict__ wqT, u16* __restrict__ woT) {
  const int bid = blockIdx.x, tid = threadIdx.x;
  if (bid < 4096) {
    int i = (bid * 256 + tid) * 4;
    float4 v = *(const float4*)&x[i];
    ushort4 p;
    p.x = f2bf(v.x); p.y = f2bf(v.y); p.z = f2bf(v.z); p.w = f2bf(v.w);
    *(ushort4*)&xb[i] = p;
    return;
  }
  __shared__ float tile[32][33];
  int t = bid - 4096;
  const float* in;
  u16* outp;
  int C, bx, by;
  if (t < 3072) { in = w_qkv; outp = wqT; C = 3072; bx = (t % 96) * 32; by = (t / 96) * 32; }
  else { t -= 3072; in = w_out; outp = woT; C = 1024; bx = (t % 32) * 32; by = (t / 32) * 32; }
  const int R = 1024;
  const int tx = tid & 31, ty = tid >> 5;
#pragma unroll
  for (int r2 = 0; r2 < 4; ++r2)
    tile[ty + r2 * 8][tx] = in[(size_t)(by + ty + r2 * 8) * C + bx + tx];
  __syncthreads();
#pragma unroll
  for (int r2 = 0; r2 < 4; ++r2)
    outp[(size_t)(bx + ty + r2 * 8) * R + by + tx] = f2bf(tile[tx][ty + r2 * 8]);
}

// ---------------- GEMM 128x128: C = A @ Bt^T + bias, QKV scatter ----------
__global__ __launch_bounds__(256, 2) void gemm_qkv(
    const u16* __restrict__ A, const u16* __restrict__ Bt,
    const float* __restrict__ bias,
    u16* __restrict__ qb, u16* __restrict__ kb, u16* __restrict__ vb,
    int M, int N, int K) {
  __shared__ u16 As[128 * 32];
  __shared__ u16 Bs[128 * 32];
  const int tid = threadIdx.x;
  const int m0 = blockIdx.x * 128;
  const int n0 = blockIdx.y * 128;
  const int lane = tid & 63, w = tid >> 6;
  const int quad = lane >> 4, l16 = lane & 15;
  const int wr = w >> 1, wc = w & 1;

  f32x4 acc[4][4] = {};

  const int r0 = tid >> 2, p0 = tid & 3;
  const int r1 = r0 + 64;
  const int c8 = p0 ^ ((r0 >> 1) & 3);
  const u16* ga0 = A + (size_t)(m0 + r0) * K + c8 * 8;
  const u16* ga1 = A + (size_t)(m0 + r1) * K + c8 * 8;
  const u16* gb0 = Bt + (size_t)(n0 + r0) * K + c8 * 8;
  const u16* gb1 = Bt + (size_t)(n0 + r1) * K + c8 * 8;
  u16* la0 = &As[tid * 8];
  u16* la1 = &As[(tid + 256) * 8];
  u16* lb0 = &Bs[tid * 8];
  u16* lb1 = &Bs[(tid + 256) * 8];

  int aoff[4], boff[4];
#pragma unroll
  for (int i = 0; i < 4; ++i) {
    int ra = wr * 64 + i * 16 + l16;
    aoff[i] = (ra * 4 + (quad ^ ((ra >> 1) & 3))) * 8;
    int rb = wc * 64 + i * 16 + l16;
    boff[i] = (rb * 4 + (quad ^ ((rb >> 1) & 3))) * 8;
  }

  const int nIter = K >> 5;
  for (int kt = 0; kt < nIter; ++kt) {
    __syncthreads();
    const int kk = kt << 5;
    GLOAD_LDS16(ga0 + kk, la0);
    GLOAD_LDS16(ga1 + kk, la1);
    GLOAD_LDS16(gb0 + kk, lb0);
    GLOAD_LDS16(gb1 + kk, lb1);
    __syncthreads();
    bf16x8 af[4], bfr[4];
#pragma unroll
    for (int i = 0; i < 4; ++i) af[i] = *(const bf16x8*)&As[aoff[i]];
#pragma unroll
    for (int j = 0; j < 4; ++j) bfr[j] = *(const bf16x8*)&Bs[boff[j]];
#pragma unroll
    for (int i = 0; i < 4; ++i)
#pragma unroll
      for (int j = 0; j < 4; ++j)
        acc[i][j] = MFMA16(af[i], bfr[j], acc[i][j]);
  }

  const int S = 2048, NH = 16;
#pragma unroll
  for (int i = 0; i < 4; ++i) {
    const int mb = m0 + wr * 64 + i * 16 + quad * 4;
#pragma unroll
    for (int j = 0; j < 4; ++j) {
      const int n = n0 + wc * 64 + j * 16 + l16;
      const float bv = bias[n];
      const int which = n >> 10;      // 0:Q 1:K 2:V (uniform per block)
      const int hn = n & 1023;
      const int h = hn >> 6, d = hn & 63;
      const int b = mb >> 11, s = mb & 2047;
      const int bh = b * NH + h;
      if (which == 2) {
        ushort4 pk;
        pk.x = f2bf(acc[i][j][0] + bv);
        pk.y = f2bf(acc[i][j][1] + bv);
        pk.z = f2bf(acc[i][j][2] + bv);
        pk.w = f2bf(acc[i][j][3] + bv);
        *(ushort4*)&vb[((size_t)bh * 64 + d) * S + s] = pk;  // V transposed
      } else {
        // Q pre-scaled by HD^-0.5 * log2(e): scores land in exp2 domain
        const float sc = (which == 0) ? 0.18033688f : 1.0f;
        u16* dst = (which == 0) ? qb : kb;
#pragma unroll
        for (int r = 0; r < 4; ++r)
          dst[((size_t)bh * S + s + r) * 64 + d] = f2bf((acc[i][j][r] + bv) * sc);
      }
    }
  }
}

// ---------------- GEMM 64x128: out = A @ Bt^T + bias (fp32 out) ----------
__global__ __launch_bounds__(256, 2) void gemm_out(
    const u16* __restrict__ A, const u16* __restrict__ Bt,
    const float* __restrict__ bias, float* __restrict__ outf,
    int M, int N, int K) {
  __shared__ u16 As[64 * 32];
  __shared__ u16 Bs[128 * 32];
  const int tid = threadIdx.x;
  const int m0 = blockIdx.x * 64;
  const int n0 = blockIdx.y * 128;
  const int lane = tid & 63, w = tid >> 6;
  const int quad = lane >> 4, l16 = lane & 15;
  const int wr = w >> 1, wc = w & 1;

  f32x4 acc[2][4] = {};

  const int r0 = tid >> 2, p0 = tid & 3;
  const int c8 = p0 ^ ((r0 >> 1) & 3);
  const u16* ga0 = A + (size_t)(m0 + r0) * K + c8 * 8;
  const u16* gb0 = Bt + (size_t)(n0 + r0) * K + c8 * 8;
  const u16* gb1 = Bt + (size_t)(n0 + r0 + 64) * K + c8 * 8;
  u16* la0 = &As[tid * 8];
  u16* lb0 = &Bs[tid * 8];
  u16* lb1 = &Bs[(tid + 256) * 8];

  int aoff[2], boff[4];
#pragma unroll
  for (int i = 0; i < 2; ++i) {
    int ra = wr * 32 + i * 16 + l16;
    aoff[i] = (ra * 4 + (quad ^ ((ra >> 1) & 3))) * 8;
  }
#pragma unroll
  for (int j = 0; j < 4; ++j) {
    int rb = wc * 64 + j * 16 + l16;
    boff[j] = (rb * 4 + (quad ^ ((rb >> 1) & 3))) * 8;
  }

  const int nIter = K >> 5;
  for (int kt = 0; kt < nIter; ++kt) {
    __syncthreads();
    const int kk = kt << 5;
    GLOAD_LDS16(ga0 + kk, la0);
    GLOAD_LDS16(gb0 + kk, lb0);
    GLOAD_LDS16(gb1 + kk, lb1);
    __syncthreads();
    bf16x8 af[2], bfr[4];
#pragma unroll
    for (int i = 0; i < 2; ++i) af[i] = *(const bf16x8*)&As[aoff[i]];
#pragma unroll
    for (int j = 0; j < 4; ++j) bfr[j] = *(const bf16x8*)&Bs[boff[j]];
#pragma unroll
    for (int i = 0; i < 2; ++i)
#pragma unroll
      for (int j = 0; j < 4; ++j)
        acc[i][j] = MFMA16(af[i], bfr[j], acc[i][j]);
  }

#pragma unroll
  for (int i = 0; i < 2; ++i) {
    const int mb = m0 + wr * 32 + i * 16 + quad * 4;
#pragma unroll
    for (int j = 0; j < 4; ++j) {
      const int n = n0 + wc * 64 + j * 16 + l16;
      const float bv = bias[n];
#pragma unroll
      for (int r = 0; r < 4; ++r)
        outf[(size_t)(mb + r) * N + n] = acc[i][j][r] + bv;
    }
  }
}

// ---------------- flash attention v6: 64 q per wave ----------------
// 2 waves x 64 q = 128 q/block, grid (NH,B,S/128) = 512 blocks, 128 threads.
// K/V fragment reads serve 2x the MFMA work vs 32q/wave (halved redundancy).
// S^T = K (Q*scale*log2e)^T, P = exp2(S^T), O^T = V^T P^T, l via ones-MFMA.
__global__ __launch_bounds__(128, 2) void attn_fa(
    const u16* __restrict__ qg, const u16* __restrict__ kg,
    const u16* __restrict__ vg, u16* __restrict__ o) {
  const int S = 2048, NH = 16;
  const int h = blockIdx.x, b = blockIdx.y, qblk = blockIdx.z;
  const int bh = b * NH + h;
  const int tid = threadIdx.x, w = tid >> 6, lane = tid & 63;
  const int quad = lane >> 4, l16 = lane & 15;

  __shared__ u16 Ks[2][4096];
  __shared__ u16 Vs[2][4096];      // V^T [d][sk]
  __shared__ u16 Ps[2][4096];      // per-wave [64 q][64 k], granule^l16 swizzle

  const int q0 = qblk * 128 + w * 64;

  // Q as B-operand, 4 q-tiles of 16
  bf16x8 qf[4][2];
#pragma unroll
  for (int qt = 0; qt < 4; ++qt) {
    const u16* qp = qg + ((size_t)bh * S + q0 + qt * 16 + l16) * 64 + quad * 8;
    qf[qt][0] = *(const bf16x8*)qp;
    qf[qt][1] = *(const bf16x8*)(qp + 32);
  }

  f32x4 accO[4][4] = {};   // [d-ct][qt]
  f32x4 accL[4] = {};      // [qt]

  bf16x8 ones;
#pragma unroll
  for (int i = 0; i < 8; ++i) ones[i] = (__bf16)1.0f;

  const u16* kbase = kg + (size_t)bh * S * 64;
  const u16* vbase = vg + (size_t)bh * 64 * S;

  // staging: 128 threads, 16 rows x 8 granules per pass, 4 passes each for K,V
  const int sr0 = tid >> 3, sp0 = tid & 7;      // sr0 in [0,16)
  const int c8s = sp0 ^ (sr0 & 7);              // same for sr0+16j
  const u16* kS[4];
  const u16* vS[4];
#pragma unroll
  for (int j = 0; j < 4; ++j) {
    kS[j] = kbase + (size_t)(sr0 + 16 * j) * 64 + c8s * 8;
    vS[j] = vbase + (size_t)(sr0 + 16 * j) * S + c8s * 8;
  }

  int koff[4][2];
#pragma unroll
  for (int ct = 0; ct < 4; ++ct) {
    int row = ct * 16 + l16;
    koff[ct][0] = (row * 8 + (quad ^ (row & 7))) * 8;
    koff[ct][1] = (row * 8 + ((quad + 4) ^ (row & 7))) * 8;
  }
  u16* Pw = Ps[w];
  int prow[4];
#pragma unroll
  for (int qt = 0; qt < 4; ++qt) prow[qt] = (qt * 16 + l16) * 64;
  int pgx[4];
#pragma unroll
  for (int ct = 0; ct < 4; ++ct) pgx[ct] = ((ct * 4 + quad) ^ l16) * 4;
  const int pr0 = ((quad * 2) ^ l16) * 4;  // frag granules: pr0, ^4, ^32, ^36

  // preload tile 0 into buffer 0
#pragma unroll
  for (int j = 0; j < 4; ++j) {
    GLOAD_LDS16(kS[j], &Ks[0][(tid + 128 * j) * 8]);
    GLOAD_LDS16(vS[j], &Vs[0][(tid + 128 * j) * 8]);
  }

  for (int kt = 0; kt < S / 64; ++kt) {
    const int cur = kt & 1;
    __syncthreads();  // drains in-flight glds (issued a full tile ago)
    if (kt + 1 < S / 64) {
      const int nb = cur ^ 1;
#pragma unroll
      for (int j = 0; j < 4; ++j) {
        GLOAD_LDS16(kS[j] + (size_t)(kt + 1) * 4096, &Ks[nb][(tid + 128 * j) * 8]);
        GLOAD_LDS16(vS[j] + (kt + 1) * 64, &Vs[nb][(tid + 128 * j) * 8]);
      }
    }
    const u16* Kc = Ks[cur];
    const u16* Vc = Vs[cur];

    // ---- per 16-key slab: QK -> exp2 -> pack P (score regs recycle) ----
#pragma unroll
    for (int ct = 0; ct < 4; ++ct) {
      bf16x8 kf0 = *(const bf16x8*)&Kc[koff[ct][0]];
      bf16x8 kf1 = *(const bf16x8*)&Kc[koff[ct][1]];
      f32x4 s[4];
#pragma unroll
      for (int qt = 0; qt < 4; ++qt) {
        s[qt] = MFMA16(kf0, qf[qt][0], f32x4{});
        s[qt] = MFMA16(kf1, qf[qt][1], s[qt]);
      }
#pragma unroll
      for (int qt = 0; qt < 4; ++qt) {
#pragma unroll
        for (int r = 0; r < 4; ++r) s[qt][r] = __builtin_amdgcn_exp2f(s[qt][r]);
        bf16x4 pk = {(__bf16)s[qt][0], (__bf16)s[qt][1],
                     (__bf16)s[qt][2], (__bf16)s[qt][3]};
        *(bf16x4*)&Pw[prow[qt] + pgx[ct]] = pk;
      }
    }

    // ---- V fragments ----
    bf16x8 vf[4][2];
#pragma unroll
    for (int ct = 0; ct < 4; ++ct) {
      vf[ct][0] = *(const bf16x8*)&Vc[koff[ct][0]];
      vf[ct][1] = *(const bf16x8*)&Vc[koff[ct][1]];
    }

    // ---- read P as B-fragments (same-wave LDS, in-order) ----
    bf16x8 pf[4][2];
#pragma unroll
    for (int qt = 0; qt < 4; ++qt) {
      bf16x4 t0 = *(const bf16x4*)&Pw[prow[qt] + pr0];
      bf16x4 t1 = *(const bf16x4*)&Pw[prow[qt] + (pr0 ^ 4)];
      bf16x4 t2 = *(const bf16x4*)&Pw[prow[qt] + (pr0 ^ 32)];
      bf16x4 t3 = *(const bf16x4*)&Pw[prow[qt] + (pr0 ^ 36)];
      pf[qt][0] = __builtin_shufflevector(t0, t1, 0, 1, 2, 3, 4, 5, 6, 7);
      pf[qt][1] = __builtin_shufflevector(t2, t3, 0, 1, 2, 3, 4, 5, 6, 7);
    }

    // ---- row sums on the matrix pipe ----
#pragma unroll
    for (int qt = 0; qt < 4; ++qt) {
      accL[qt] = MFMA16(ones, pf[qt][0], accL[qt]);
      accL[qt] = MFMA16(ones, pf[qt][1], accL[qt]);
    }

    // ---- O^T += V^T P^T ----
#pragma unroll
    for (int ct = 0; ct < 4; ++ct)
#pragma unroll
      for (int qt = 0; qt < 4; ++qt) {
        accO[ct][qt] = MFMA16(vf[ct][0], pf[qt][0], accO[ct][qt]);
        accO[ct][qt] = MFMA16(vf[ct][1], pf[qt][1], accO[ct][qt]);
      }
  }

  float inv[4];
#pragma unroll
  for (int qt = 0; qt < 4; ++qt) inv[qt] = 1.f / accL[qt][0];

#pragma unroll
  for (int ct = 0; ct < 4; ++ct)
#pragma unroll
    for (int qt = 0; qt < 4; ++qt) {
      const int s = q0 + qt * 16 + l16;
      ushort4 pk;
      pk.x = f2bf(accO[ct][qt][0] * inv[qt]);
      pk.y = f2bf(accO[ct][qt][1] * inv[qt]);
      pk.z = f2bf(accO[ct][qt][2] * inv[qt]);
      pk.w = f2bf(accO[ct][qt][3] * inv[qt]);
      *(ushort4*)&o[(size_t)(b * S + s) * 1024 + h * 64 + ct * 16 + quad * 4] = pk;
    }
}

// ---------------- launch ----------------

extern "C" void kernel_launch(void* const* d_in, const int* in_sizes, int n_in,
                              void* d_out, int out_size, void* d_ws, size_t ws_size,
                              hipStream_t stream) {
  const float* x = (const float*)d_in[0];
  const float* w_qkv = (const float*)d_in[1];
  const float* b_qkv = (const float*)d_in[2];
  const float* w_out = (const float*)d_in[3];
  const float* b_out = (const float*)d_in[4];
  float* out = (float*)d_out;

  u16* xb = (u16*)d_ws;                 // [4096,1024]
  u16* wqT = xb + 4096 * 1024;          // [3072,1024]
  u16* woT = wqT + 3072 * 1024;         // [1024,1024]
  u16* qb = woT + 1024 * 1024;          // [32,2048,64] (pre-scaled)
  u16* kb = qb + 4194304;               // [32,2048,64]
  u16* vb = kb + 4194304;               // [32,64,2048]
  u16* ao = vb + 4194304;               // [4096,1024]

  prep<<<8192, 256, 0, stream>>>(x, w_qkv, w_out, xb, wqT, woT);
  gemm_qkv<<<dim3(32, 24), 256, 0, stream>>>(xb, wqT, b_qkv, qb, kb, vb,
                                             4096, 3072, 1024);
  attn_fa<<<dim3(16, 2, 16), 128, 0, stream>>>(qb, kb, vb, ao);
  gemm_out<<<dim3(64, 8), 256, 0, stream>>>(ao, woT, b_out, out,
                                            4096, 1024, 1024);
}

// Round 8
// 187.201 us; speedup vs baseline: 1.0830x; 1.0830x over previous
//
#include <hip/hip_runtime.h>
#include <cstdint>

using u16 = unsigned short;
typedef __bf16 bf16x8 __attribute__((ext_vector_type(8)));
typedef __bf16 bf16x4 __attribute__((ext_vector_type(4)));
typedef float f32x4 __attribute__((ext_vector_type(4)));

#define MFMA16(a, b, c) __builtin_amdgcn_mfma_f32_16x16x32_bf16((a), (b), (c), 0, 0, 0)

__device__ __forceinline__ u16 f2bf(float f) {
  union { float f; uint32_t u; } c; c.f = f;
  uint32_t u = c.u;
  u += 0x7fffu + ((u >> 16) & 1u);   // RNE
  return (u16)(u >> 16);
}

#if __has_builtin(__builtin_amdgcn_global_load_lds)
#define GLOAD_LDS16(g, l)                                                      \
  __builtin_amdgcn_global_load_lds(                                            \
      (__attribute__((address_space(1))) void*)(g),                            \
      (__attribute__((address_space(3))) void*)(l), 16, 0, 0)
#else
#define GLOAD_LDS16(g, l) do { *(uint4*)(l) = *(const uint4*)(g); } while (0)
#endif

// ---------------- fused prep: x->bf16, w_qkv^T->bf16, w_out^T->bf16 --------
__global__ __launch_bounds__(256) void prep(
    const float* __restrict__ x, const float* __restrict__ w_qkv,
    const float* __restrict__ w_out, u16* __restrict__ xb,
    u16* __restrict__ wqT, u16* __restrict__ woT) {
  const int bid = blockIdx.x, tid = threadIdx.x;
  if (bid < 4096) {
    int i = (bid * 256 + tid) * 4;
    float4 v = *(const float4*)&x[i];
    ushort4 p;
    p.x = f2bf(v.x); p.y = f2bf(v.y); p.z = f2bf(v.z); p.w = f2bf(v.w);
    *(ushort4*)&xb[i] = p;
    return;
  }
  __shared__ float tile[32][33];
  int t = bid - 4096;
  const float* in;
  u16* outp;
  int C, bx, by;
  if (t < 3072) { in = w_qkv; outp = wqT; C = 3072; bx = (t % 96) * 32; by = (t / 96) * 32; }
  else { t -= 3072; in = w_out; outp = woT; C = 1024; bx = (t % 32) * 32; by = (t / 32) * 32; }
  const int R = 1024;
  const int tx = tid & 31, ty = tid >> 5;
#pragma unroll
  for (int r2 = 0; r2 < 4; ++r2)
    tile[ty + r2 * 8][tx] = in[(size_t)(by + ty + r2 * 8) * C + bx + tx];
  __syncthreads();
#pragma unroll
  for (int r2 = 0; r2 < 4; ++r2)
    outp[(size_t)(bx + ty + r2 * 8) * R + by + tx] = f2bf(tile[tx][ty + r2 * 8]);
}

// ---------------- GEMM 128x128: C = A @ Bt^T + bias, QKV scatter ----------
__global__ __launch_bounds__(256, 2) void gemm_qkv(
    const u16* __restrict__ A, const u16* __restrict__ Bt,
    const float* __restrict__ bias,
    u16* __restrict__ qb, u16* __restrict__ kb, u16* __restrict__ vb,
    int M, int N, int K) {
  __shared__ u16 As[128 * 32];
  __shared__ u16 Bs[128 * 32];
  const int tid = threadIdx.x;
  const int m0 = blockIdx.x * 128;
  const int n0 = blockIdx.y * 128;
  const int lane = tid & 63, w = tid >> 6;
  const int quad = lane >> 4, l16 = lane & 15;
  const int wr = w >> 1, wc = w & 1;

  f32x4 acc[4][4] = {};

  const int r0 = tid >> 2, p0 = tid & 3;
  const int r1 = r0 + 64;
  const int c8 = p0 ^ ((r0 >> 1) & 3);
  const u16* ga0 = A + (size_t)(m0 + r0) * K + c8 * 8;
  const u16* ga1 = A + (size_t)(m0 + r1) * K + c8 * 8;
  const u16* gb0 = Bt + (size_t)(n0 + r0) * K + c8 * 8;
  const u16* gb1 = Bt + (size_t)(n0 + r1) * K + c8 * 8;
  u16* la0 = &As[tid * 8];
  u16* la1 = &As[(tid + 256) * 8];
  u16* lb0 = &Bs[tid * 8];
  u16* lb1 = &Bs[(tid + 256) * 8];

  int aoff[4], boff[4];
#pragma unroll
  for (int i = 0; i < 4; ++i) {
    int ra = wr * 64 + i * 16 + l16;
    aoff[i] = (ra * 4 + (quad ^ ((ra >> 1) & 3))) * 8;
    int rb = wc * 64 + i * 16 + l16;
    boff[i] = (rb * 4 + (quad ^ ((rb >> 1) & 3))) * 8;
  }

  const int nIter = K >> 5;
  for (int kt = 0; kt < nIter; ++kt) {
    __syncthreads();
    const int kk = kt << 5;
    GLOAD_LDS16(ga0 + kk, la0);
    GLOAD_LDS16(ga1 + kk, la1);
    GLOAD_LDS16(gb0 + kk, lb0);
    GLOAD_LDS16(gb1 + kk, lb1);
    __syncthreads();
    bf16x8 af[4], bfr[4];
#pragma unroll
    for (int i = 0; i < 4; ++i) af[i] = *(const bf16x8*)&As[aoff[i]];
#pragma unroll
    for (int j = 0; j < 4; ++j) bfr[j] = *(const bf16x8*)&Bs[boff[j]];
#pragma unroll
    for (int i = 0; i < 4; ++i)
#pragma unroll
      for (int j = 0; j < 4; ++j)
        acc[i][j] = MFMA16(af[i], bfr[j], acc[i][j]);
  }

  const int S = 2048, NH = 16;
#pragma unroll
  for (int i = 0; i < 4; ++i) {
    const int mb = m0 + wr * 64 + i * 16 + quad * 4;
#pragma unroll
    for (int j = 0; j < 4; ++j) {
      const int n = n0 + wc * 64 + j * 16 + l16;
      const float bv = bias[n];
      const int which = n >> 10;      // 0:Q 1:K 2:V (uniform per block)
      const int hn = n & 1023;
      const int h = hn >> 6, d = hn & 63;
      const int b = mb >> 11, s = mb & 2047;
      const int bh = b * NH + h;
      if (which == 2) {
        ushort4 pk;
        pk.x = f2bf(acc[i][j][0] + bv);
        pk.y = f2bf(acc[i][j][1] + bv);
        pk.z = f2bf(acc[i][j][2] + bv);
        pk.w = f2bf(acc[i][j][3] + bv);
        *(ushort4*)&vb[((size_t)bh * 64 + d) * S + s] = pk;  // V transposed
      } else {
        // Q pre-scaled by HD^-0.5 * log2(e): scores land in exp2 domain
        const float sc = (which == 0) ? 0.18033688f : 1.0f;
        u16* dst = (which == 0) ? qb : kb;
#pragma unroll
        for (int r = 0; r < 4; ++r)
          dst[((size_t)bh * S + s + r) * 64 + d] = f2bf((acc[i][j][r] + bv) * sc);
      }
    }
  }
}

// ---------------- GEMM 64x128: out = A @ Bt^T + bias (fp32 out) ----------
__global__ __launch_bounds__(256, 2) void gemm_out(
    const u16* __restrict__ A, const u16* __restrict__ Bt,
    const float* __restrict__ bias, float* __restrict__ outf,
    int M, int N, int K) {
  __shared__ u16 As[64 * 32];
  __shared__ u16 Bs[128 * 32];
  const int tid = threadIdx.x;
  const int m0 = blockIdx.x * 64;
  const int n0 = blockIdx.y * 128;
  const int lane = tid & 63, w = tid >> 6;
  const int quad = lane >> 4, l16 = lane & 15;
  const int wr = w >> 1, wc = w & 1;

  f32x4 acc[2][4] = {};

  const int r0 = tid >> 2, p0 = tid & 3;
  const int c8 = p0 ^ ((r0 >> 1) & 3);
  const u16* ga0 = A + (size_t)(m0 + r0) * K + c8 * 8;
  const u16* gb0 = Bt + (size_t)(n0 + r0) * K + c8 * 8;
  const u16* gb1 = Bt + (size_t)(n0 + r0 + 64) * K + c8 * 8;
  u16* la0 = &As[tid * 8];
  u16* lb0 = &Bs[tid * 8];
  u16* lb1 = &Bs[(tid + 256) * 8];

  int aoff[2], boff[4];
#pragma unroll
  for (int i = 0; i < 2; ++i) {
    int ra = wr * 32 + i * 16 + l16;
    aoff[i] = (ra * 4 + (quad ^ ((ra >> 1) & 3))) * 8;
  }
#pragma unroll
  for (int j = 0; j < 4; ++j) {
    int rb = wc * 64 + j * 16 + l16;
    boff[j] = (rb * 4 + (quad ^ ((rb >> 1) & 3))) * 8;
  }

  const int nIter = K >> 5;
  for (int kt = 0; kt < nIter; ++kt) {
    __syncthreads();
    const int kk = kt << 5;
    GLOAD_LDS16(ga0 + kk, la0);
    GLOAD_LDS16(gb0 + kk, lb0);
    GLOAD_LDS16(gb1 + kk, lb1);
    __syncthreads();
    bf16x8 af[2], bfr[4];
#pragma unroll
    for (int i = 0; i < 2; ++i) af[i] = *(const bf16x8*)&As[aoff[i]];
#pragma unroll
    for (int j = 0; j < 4; ++j) bfr[j] = *(const bf16x8*)&Bs[boff[j]];
#pragma unroll
    for (int i = 0; i < 2; ++i)
#pragma unroll
      for (int j = 0; j < 4; ++j)
        acc[i][j] = MFMA16(af[i], bfr[j], acc[i][j]);
  }

#pragma unroll
  for (int i = 0; i < 2; ++i) {
    const int mb = m0 + wr * 32 + i * 16 + quad * 4;
#pragma unroll
    for (int j = 0; j < 4; ++j) {
      const int n = n0 + wc * 64 + j * 16 + l16;
      const float bv = bias[n];
#pragma unroll
      for (int r = 0; r < 4; ++r)
        outf[(size_t)(mb + r) * N + n] = acc[i][j][r] + bv;
    }
  }
}

// ---------------- flash attention v7: barrier-free per-wave pipeline -------
// Block = 4 waves sharing 64 q; wave w owns keys [w*512,(w+1)*512) in 16
// tiles of 32. K staged per-wave (private 2x4KB LDS dbuf via DMA); V frags
// register-prefetched from global; explicit s_waitcnt vmcnt(8) pipelining
// (no __syncthreads in the K-loop). No max-shift softmax => partial O/l from
// disjoint key ranges reduce by pure addition in a 3-step LDS tree epilogue.
__global__ __launch_bounds__(256, 2) void attn_fa(
    const u16* __restrict__ qg, const u16* __restrict__ kg,
    const u16* __restrict__ vg, u16* __restrict__ o) {
  const int S = 2048, NH = 16;
  const int h = blockIdx.x, b = blockIdx.y, qblk = blockIdx.z;
  const int bh = b * NH + h;
  const int tid = threadIdx.x, w = tid >> 6, lane = tid & 63;
  const int quad = lane >> 4, l16 = lane & 15;

  __shared__ __align__(16) u16 smem[24576];  // 48 KB
  u16* Kw0 = smem + w * 2048;                // wave-private K buf0 (4 KB)
  u16* Kw1 = smem + 8192 + w * 2048;         // wave-private K buf1
  u16* Pw  = smem + 16384 + w * 2048;        // wave-private P [64q][32k] (4 KB)

  const int q0 = qblk * 64;
  bf16x8 qf[4][2];
#pragma unroll
  for (int qt = 0; qt < 4; ++qt) {
    const u16* qp = qg + ((size_t)bh * S + q0 + qt * 16 + l16) * 64 + quad * 8;
    qf[qt][0] = *(const bf16x8*)qp;
    qf[qt][1] = *(const bf16x8*)(qp + 32);
  }

  const u16* kbase = kg + (size_t)bh * S * 64;
  const u16* vbase = vg + (size_t)bh * 64 * S;
  const int key0w = w * 512;

  // K-DMA source mapping: inst j stages rows j*8+sr, logical granule sc
  const int sr = lane >> 3;
  const int sc = (lane & 7) ^ sr;

  // K fragment offsets (u16 units): row = ct*16+l16, d-halves dh=0,1
  int koff[2][2];
#pragma unroll
  for (int ct = 0; ct < 2; ++ct)
#pragma unroll
    for (int dh = 0; dh < 2; ++dh) {
      int row = ct * 16 + l16;
      koff[ct][dh] = (row * 8 + ((dh * 4 + quad) ^ (l16 & 7))) * 8;
    }

  // P swizzle (2-bit): write b64 groups 4-uniform, read b128 groups 8-uniform
  const int swz = (l16 ^ (l16 >> 2)) & 3;
  int pwA[4], pwB[4], prd[4];
#pragma unroll
  for (int qt = 0; qt < 4; ++qt) {
    int rowb = (qt * 16 + l16) * 32;
    pwA[qt] = rowb + (((quad >> 1) ^ swz)) * 8 + (quad & 1) * 4;       // keys ct0
    pwB[qt] = rowb + (((2 + (quad >> 1)) ^ swz)) * 8 + (quad & 1) * 4; // keys ct1
    prd[qt] = rowb + ((quad ^ swz)) * 8;                               // B-frag
  }

  f32x4 accO[4][4] = {};   // [d-ct][qt]
  f32x4 accL[4] = {};
  bf16x8 ones;
#pragma unroll
  for (int i = 0; i < 8; ++i) ones[i] = (__bf16)1.0f;

  bf16x8 vfA[4], vfB[4];

  auto kdma = [&](int t, u16* BUF) {
    const int kk = key0w + (t & 15) * 32;
#pragma unroll
    for (int j = 0; j < 4; ++j)
      GLOAD_LDS16(kbase + (size_t)(kk + j * 8 + sr) * 64 + sc * 8,
                  &BUF[j * 512 + lane * 8]);
  };
  auto vload = [&](int t, bf16x8 (&VF)[4]) {
    const int kk = key0w + (t & 15) * 32;
#pragma unroll
    for (int ct = 0; ct < 4; ++ct)
      VF[ct] = *(const bf16x8*)(vbase + (size_t)(ct * 16 + l16) * S + kk + quad * 8);
  };
  auto tile = [&](int t, u16* KBUF, bf16x8 (&VF)[4]) {
    asm volatile("s_waitcnt vmcnt(8)" ::: "memory");
    bf16x8 kf00 = *(const bf16x8*)&KBUF[koff[0][0]];
    bf16x8 kf01 = *(const bf16x8*)&KBUF[koff[0][1]];
    bf16x8 kf10 = *(const bf16x8*)&KBUF[koff[1][0]];
    bf16x8 kf11 = *(const bf16x8*)&KBUF[koff[1][1]];
    f32x4 s0[4], s1[4];
    f32x4 z = {};
#pragma unroll
    for (int qt = 0; qt < 4; ++qt) {
      s0[qt] = MFMA16(kf00, qf[qt][0], z);
      s0[qt] = MFMA16(kf01, qf[qt][1], s0[qt]);
      s1[qt] = MFMA16(kf10, qf[qt][0], z);
      s1[qt] = MFMA16(kf11, qf[qt][1], s1[qt]);
    }
#pragma unroll
    for (int qt = 0; qt < 4; ++qt)
#pragma unroll
      for (int r = 0; r < 4; ++r) {
        s0[qt][r] = __builtin_amdgcn_exp2f(s0[qt][r]);
        s1[qt][r] = __builtin_amdgcn_exp2f(s1[qt][r]);
      }
#pragma unroll
    for (int qt = 0; qt < 4; ++qt) {
      bf16x4 a = {(__bf16)s0[qt][0], (__bf16)s0[qt][1],
                  (__bf16)s0[qt][2], (__bf16)s0[qt][3]};
      *(bf16x4*)&Pw[pwA[qt]] = a;
      bf16x4 c = {(__bf16)s1[qt][0], (__bf16)s1[qt][1],
                  (__bf16)s1[qt][2], (__bf16)s1[qt][3]};
      *(bf16x4*)&Pw[pwB[qt]] = c;
    }
    bf16x8 pf[4];
#pragma unroll
    for (int qt = 0; qt < 4; ++qt) pf[qt] = *(const bf16x8*)&Pw[prd[qt]];
#pragma unroll
    for (int qt = 0; qt < 4; ++qt) accL[qt] = MFMA16(ones, pf[qt], accL[qt]);
#pragma unroll
    for (int ct = 0; ct < 4; ++ct)
#pragma unroll
      for (int qt = 0; qt < 4; ++qt)
        accO[ct][qt] = MFMA16(VF[ct], pf[qt], accO[ct][qt]);
    asm volatile("s_waitcnt lgkmcnt(0)" ::: "memory");
    kdma(t + 2, KBUF);
    vload(t + 2, VF);
  };

  kdma(0, Kw0); vload(0, vfA);
  kdma(1, Kw1); vload(1, vfB);
  for (int i = 0; i < 8; ++i) {
    tile(2 * i, Kw0, vfA);
    tile(2 * i + 1, Kw1, vfB);
  }

  // ---- cross-wave reduction of partial O and l (pure sums) ----
  f32x4 lv = {accL[0][0], accL[1][0], accL[2][0], accL[3][0]};
  float* scr = (float*)smem;  // 12288 floats; region r at r*4352
  __syncthreads();
  if (w & 1) {
    float* rb = scr + (w >> 1) * 4352;
#pragma unroll
    for (int ct = 0; ct < 4; ++ct)
#pragma unroll
      for (int qt = 0; qt < 4; ++qt)
        *(f32x4*)&rb[((ct * 4 + qt) * 64 + lane) * 4] = accO[ct][qt];
    *(f32x4*)&rb[(16 * 64 + lane) * 4] = lv;
  }
  __syncthreads();
  if (!(w & 1)) {
    float* rb = scr + (w >> 1) * 4352;
#pragma unroll
    for (int ct = 0; ct < 4; ++ct)
#pragma unroll
      for (int qt = 0; qt < 4; ++qt)
        accO[ct][qt] += *(const f32x4*)&rb[((ct * 4 + qt) * 64 + lane) * 4];
    lv += *(const f32x4*)&rb[(16 * 64 + lane) * 4];
  }
  __syncthreads();
  if (w == 2) {
    float* rb = scr;
#pragma unroll
    for (int ct = 0; ct < 4; ++ct)
#pragma unroll
      for (int qt = 0; qt < 4; ++qt)
        *(f32x4*)&rb[((ct * 4 + qt) * 64 + lane) * 4] = accO[ct][qt];
    *(f32x4*)&rb[(16 * 64 + lane) * 4] = lv;
  }
  __syncthreads();
  if (w == 0) {
    float* rb = scr;
#pragma unroll
    for (int ct = 0; ct < 4; ++ct)
#pragma unroll
      for (int qt = 0; qt < 4; ++qt)
        accO[ct][qt] += *(const f32x4*)&rb[((ct * 4 + qt) * 64 + lane) * 4];
    lv += *(const f32x4*)&rb[(16 * 64 + lane) * 4];
    float inv[4];
#pragma unroll
    for (int qt = 0; qt < 4; ++qt) inv[qt] = 1.f / lv[qt];
#pragma unroll
    for (int ct = 0; ct < 4; ++ct)
#pragma unroll
      for (int qt = 0; qt < 4; ++qt) {
        const int s = q0 + qt * 16 + l16;
        ushort4 pk;
        pk.x = f2bf(accO[ct][qt][0] * inv[qt]);
        pk.y = f2bf(accO[ct][qt][1] * inv[qt]);
        pk.z = f2bf(accO[ct][qt][2] * inv[qt]);
        pk.w = f2bf(accO[ct][qt][3] * inv[qt]);
        *(ushort4*)&o[(size_t)(b * S + s) * 1024 + h * 64 + ct * 16 + quad * 4] = pk;
      }
  }
}

// ---------------- launch ----------------

extern "C" void kernel_launch(void* const* d_in, const int* in_sizes, int n_in,
                              void* d_out, int out_size, void* d_ws, size_t ws_size,
                              hipStream_t stream) {
  const float* x = (const float*)d_in[0];
  const float* w_qkv = (const float*)d_in[1];
  const float* b_qkv = (const float*)d_in[2];
  const float* w_out = (const float*)d_in[3];
  const float* b_out = (const float*)d_in[4];
  float* out = (float*)d_out;

  u16* xb = (u16*)d_ws;                 // [4096,1024]
  u16* wqT = xb + 4096 * 1024;          // [3072,1024]
  u16* woT = wqT + 3072 * 1024;         // [1024,1024]
  u16* qb = woT + 1024 * 1024;          // [32,2048,64] (pre-scaled)
  u16* kb = qb + 4194304;               // [32,2048,64]
  u16* vb = kb + 4194304;               // [32,64,2048]
  u16* ao = vb + 4194304;               // [4096,1024]

  prep<<<8192, 256, 0, stream>>>(x, w_qkv, w_out, xb, wqT, woT);
  gemm_qkv<<<dim3(32, 24), 256, 0, stream>>>(xb, wqT, b_qkv, qb, kb, vb,
                                             4096, 3072, 1024);
  attn_fa<<<dim3(16, 2, 32), 256, 0, stream>>>(qb, kb, vb, ao);
  gemm_out<<<dim3(64, 8), 256, 0, stream>>>(ao, woT, b_out, out,
                                            4096, 1024, 1024);
}